// Round 2
// baseline (3612.781 us; speedup 1.0000x reference)
//
#include <hip/hip_runtime.h>

#define NN 100000
#define NE 1600000
#define DIM 128
#define NT 13            // src tiles: src>>13 -> 8192 rows = 2 MB bf16 per tile (fits 4 MB L2)
#define SH 13
#define LEN (NN * NT)    // buckets, rowgroup-major: idx = (dst>>3)*104 + tt*8 + (dst&7)
#define NB_SCAN ((LEN + 1023) / 1024)
#define FST 140          // smF row stride (dwords): 16B-aligned
#define NGRP 12500       // rowgroups (NN/8)
#define PW 8             // dst-window passes in k_scat
#define GW ((NGRP + PW - 1) / PW)

typedef __attribute__((ext_vector_type(8))) short short8;
typedef __attribute__((ext_vector_type(4))) float f4;
typedef __attribute__((ext_vector_type(4))) unsigned u4;

__device__ __forceinline__ unsigned short f2bf(float f){
  unsigned x = __float_as_uint(f);
  x += 0x7fffu + ((x >> 16) & 1u);
  return (unsigned short)(x >> 16);
}
__device__ __forceinline__ unsigned pack2(float lo, float hi){
  return ((unsigned)f2bf(hi) << 16) | (unsigned)f2bf(lo);
}
__device__ __forceinline__ float blo(unsigned u){ return __uint_as_float(u << 16); }
__device__ __forceinline__ float bhi(unsigned u){ return __uint_as_float(u & 0xffff0000u); }
__device__ __forceinline__ short8 cvt8(f4 a, f4 b){
  short8 r;
  #pragma unroll
  for (int j = 0; j < 4; ++j){ r[j] = (short)f2bf(a[j]); r[j+4] = (short)f2bf(b[j]); }
  return r;
}

// ---------------- fallback sentinel ----------------
__global__ void k_sentinel(float* __restrict__ out, int n){
  int i = blockIdx.x * blockDim.x + threadIdx.x;
  if (i < n) out[i] = 12345.0f;
}

// ---------------- x fp32 -> bf16x2 ----------------
__global__ void k_cvt(const float* __restrict__ x, unsigned* __restrict__ xb){
  int i = blockIdx.x * blockDim.x + threadIdx.x;   // i < NN*16
  if (i >= NN * 16) return;
  f4 a = ((const f4*)x)[2 * i];
  f4 b = ((const f4*)x)[2 * i + 1];
  u4 o;
  o[0] = pack2(a[0], a[1]); o[1] = pack2(a[2], a[3]);
  o[2] = pack2(b[0], b[1]); o[3] = pack2(b[2], b[3]);
  ((u4*)xb)[i] = o;
}

// ---------------- histogram (rowgroup-major buckets) ----------------
__global__ void k_hist(const int* __restrict__ src, const int* __restrict__ dst,
                       int* __restrict__ cnt){
  int i = blockIdx.x * blockDim.x + threadIdx.x;
  if (i < NE){
    int s = src[i], d = dst[i];
    atomicAdd(&cnt[(d >> 3) * 104 + (s >> SH) * 8 + (d & 7)], 1);
  }
}

__global__ void k_deg(const int* __restrict__ cnt, int* __restrict__ deg){
  int i = blockIdx.x * blockDim.x + threadIdx.x;
  if (i < NN){
    int g = i >> 3, r = i & 7;
    int s = 0;
    #pragma unroll
    for (int tt = 0; tt < NT; ++tt) s += cnt[g * 104 + tt * 8 + r];
    deg[i] = s;
  }
}

__global__ void k_bsum(const int* __restrict__ cnt, int* __restrict__ bsum, int len){
  __shared__ int sh[256];
  int t = threadIdx.x, b = blockIdx.x;
  int base = b * 1024 + t * 4;
  int s = 0;
  #pragma unroll
  for (int j = 0; j < 4; ++j){ int i = base + j; if (i < len) s += cnt[i]; }
  sh[t] = s; __syncthreads();
  for (int off = 128; off > 0; off >>= 1){
    if (t < off) sh[t] += sh[t + off];
    __syncthreads();
  }
  if (t == 0) bsum[b] = sh[0];
}

__global__ void k_scanp(const int* __restrict__ bsum, int* __restrict__ boff, int nb){
  __shared__ int sh[256];
  int t = threadIdx.x;
  int chunk = (nb + 255) / 256;
  int s = 0;
  for (int j = 0; j < chunk; ++j){ int i = t * chunk + j; if (i < nb) s += bsum[i]; }
  sh[t] = s; __syncthreads();
  int tin = s;
  for (int off = 1; off < 256; off <<= 1){
    int u = (t >= off) ? sh[t - off] : 0;
    __syncthreads();
    sh[t] += u;
    __syncthreads();
  }
  int run = sh[t] - tin;
  for (int j = 0; j < chunk; ++j){
    int i = t * chunk + j;
    if (i < nb){ boff[i] = run; run += bsum[i]; }
  }
}

__global__ void k_scanf(const int* __restrict__ cnt, const int* __restrict__ boff,
                        int* __restrict__ rp, int* __restrict__ pos, int len){
  __shared__ int sh[256];
  int t = threadIdx.x, b = blockIdx.x;
  int base = b * 1024 + t * 4;
  int c[4]; int s = 0;
  #pragma unroll
  for (int j = 0; j < 4; ++j){ int i = base + j; c[j] = (i < len) ? cnt[i] : 0; s += c[j]; }
  sh[t] = s; __syncthreads();
  int tin = s;
  for (int off = 1; off < 256; off <<= 1){
    int u = (t >= off) ? sh[t - off] : 0;
    __syncthreads();
    sh[t] += u;
    __syncthreads();
  }
  int run = boff[b] + sh[t] - tin;
  #pragma unroll
  for (int j = 0; j < 4; ++j){
    int i = base + j;
    if (i < len){
      rp[i] = run; pos[i] = run; run += c[j];
      if (i == len - 1) rp[len] = run;
    }
  }
}

// ---------------- direct dst-windowed scatter to ss32 -------------------------
// PW sequential passes; pass p writes only rowgroups [p*GW,(p+1)*GW) ->
// contiguous window stays L2-resident. Records are fully resolved:
// rec = (src<<8) | (dst&7)  -- src*256 is the Xb byte offset, low 3 bits the
// LDS accumulator row. k_fused needs NO tile bookkeeping at consume time.
__global__ __launch_bounds__(256)
void k_scat(const int* __restrict__ src, const int* __restrict__ dst,
            int* __restrict__ pos, unsigned* __restrict__ ss32){
  int tid = blockIdx.x * 256 + threadIdx.x;
  int stride = gridDim.x * 256;
  for (int p = 0; p < PW; ++p){
    int glo = p * GW, ghi = glo + GW;
    for (int i = tid; i < NE; i += stride){
      int d = dst[i];
      int g = d >> 3;
      if (g >= glo && g < ghi){
        int s = src[i];
        int b = g * 104 + ((s >> SH) << 3) + (d & 7);
        int q = atomicAdd(&pos[b], 1);
        ss32[q] = ((unsigned)s << 8) | (unsigned)(d & 7);
      }
    }
  }
}

// ---------------- W packing ----------------
template<int NB16>
__global__ void k_pack(const float* __restrict__ Wl,
                       const float* __restrict__ Wr,
                       unsigned short* __restrict__ Bp){
  constexpr int DOUT = NB16 * 16;
  int idx = blockIdx.x * blockDim.x + threadIdx.x;
  if (idx >= 8 * NB16 * 64) return;
  int lane = idx & 63;
  int nb = (idx >> 6) % NB16;
  int ks = idx / (64 * NB16);
  int n = nb * 16 + (lane & 15);
  int k0 = ks * 32 + (lane >> 4) * 8;
  short8 v;
  #pragma unroll
  for (int j = 0; j < 8; ++j){
    int k = k0 + j;
    float w = (k < 128) ? Wl[k * DOUT + n] : Wr[(k - 128) * DOUT + n];
    v[j] = (short)f2bf(w);
  }
  ((short8*)Bp)[idx] = v;
}

// ---------------- fused tiled mean-aggregate + dual-GEMM (+BN+ReLU) ----------
// Per edge (wave-cooperative): 1 coalesced 256B bf16 row load + 2 bit-extracts
// + 2 ds_add_f32 (LDS float atomics, no return -> no RMW chain, no flush
// branch). The old cur/cx/cy register cache + ADV tile walk cost ~20 VALU/edge
// because segments averaged 1.2 edges; this body is ~6 instrs/edge.
template<int NB16, bool DO_BN>
__global__ __launch_bounds__(256, 8)
void k_fused(const unsigned* __restrict__ Xb,
             const int* __restrict__ rp2, const unsigned* __restrict__ ss32,
             const int* __restrict__ deg,
             const unsigned short* __restrict__ Bp,
             const float* __restrict__ bias,
             const float* __restrict__ bg, const float* __restrict__ bb,
             const float* __restrict__ bm, const float* __restrict__ bv,
             unsigned short* __restrict__ OutB, float* __restrict__ OutF){
  constexpr int DOUT = NB16 * 16;
  constexpr int NBW = NB16 / 4;
  __shared__ float smF[32][FST];
  const int t = threadIdx.x;
  const int lane = t & 63;
  const int wv = t >> 6;
  const int m0 = blockIdx.x * 32;
  const int g = blockIdx.x * 4 + wv;      // rowgroup owned by this wave

  for (int i = t; i < 32 * FST; i += 256) (&smF[0][0])[i] = 0.f;
  __syncthreads();

  float* const base = &smF[wv * 8][0];
  const char* const Xc = (const char*)Xb;
  const unsigned lane4 = (unsigned)lane * 4u;

  int e   = rp2[g * 104];
  int end = rp2[g * 104 + 104];

  #define EDGE(rec) { \
    unsigned _u = *(const unsigned*)(Xc + ((rec) & 0xFFFFFF00u) + lane4); \
    float* _p = base + ((rec) & 7u) * FST + 2 * lane; \
    atomicAdd(_p, blo(_u)); atomicAdd(_p + 1, bhi(_u)); }

  // head peel to 16B record alignment
  while (e < end && (e & 3)){
    unsigned rec = (unsigned)__builtin_amdgcn_readfirstlane((int)ss32[e]);
    EDGE(rec);
    ++e;
  }
  // body: 8 records per iteration (two aligned 16B record loads)
  while (e + 8 <= end){
    u4 qa = *(const u4*)(ss32 + e);
    u4 qb = *(const u4*)(ss32 + e + 4);
    unsigned r[8];
    r[0] = (unsigned)__builtin_amdgcn_readfirstlane((int)qa[0]);
    r[1] = (unsigned)__builtin_amdgcn_readfirstlane((int)qa[1]);
    r[2] = (unsigned)__builtin_amdgcn_readfirstlane((int)qa[2]);
    r[3] = (unsigned)__builtin_amdgcn_readfirstlane((int)qa[3]);
    r[4] = (unsigned)__builtin_amdgcn_readfirstlane((int)qb[0]);
    r[5] = (unsigned)__builtin_amdgcn_readfirstlane((int)qb[1]);
    r[6] = (unsigned)__builtin_amdgcn_readfirstlane((int)qb[2]);
    r[7] = (unsigned)__builtin_amdgcn_readfirstlane((int)qb[3]);
    unsigned u[8];
    #pragma unroll
    for (int i = 0; i < 8; ++i)
      u[i] = *(const unsigned*)(Xc + (r[i] & 0xFFFFFF00u) + lane4);
    #pragma unroll
    for (int i = 0; i < 8; ++i){
      float* p = base + (r[i] & 7u) * FST + 2 * lane;
      atomicAdd(p, blo(u[i]));
      atomicAdd(p + 1, bhi(u[i]));
    }
    e += 8;
  }
  // tail
  while (e < end){
    unsigned rec = (unsigned)__builtin_amdgcn_readfirstlane((int)ss32[e]);
    EDGE(rec);
    ++e;
  }
  #undef EDGE
  __syncthreads();

  // normalize
  {
    int row = t >> 3;
    int d = deg[m0 + row];
    float inv = (d > 0) ? 1.f / (float)d : 0.f;
    float* pr = &smF[row][(t & 7) * 16];
    #pragma unroll
    for (int i = 0; i < 16; ++i) pr[i] *= inv;
  }
  __syncthreads();

  // ---- phase 2: dual GEMM ----
  const int q2 = lane >> 4, lr = lane & 15;
  const short8* pb = (const short8*)Bp + lane;
  f4 acc[2][NBW];
  #pragma unroll
  for (int gg = 0; gg < 2; ++gg)
    #pragma unroll
    for (int j = 0; j < NBW; ++j)
      acc[gg][j] = (f4){0.f, 0.f, 0.f, 0.f};

  #pragma unroll
  for (int ks = 0; ks < 4; ++ks){
    const float* r0 = &smF[lr][ks * 32 + q2 * 8];
    const float* r1 = &smF[lr + 16][ks * 32 + q2 * 8];
    short8 a0 = cvt8(*(const f4*)r0, *(const f4*)(r0 + 4));
    short8 a1 = cvt8(*(const f4*)r1, *(const f4*)(r1 + 4));
    #pragma unroll
    for (int j = 0; j < NBW; ++j){
      int nb2 = wv * NBW + j;
      short8 b = pb[(ks * NB16 + nb2) * 64];
      acc[0][j] = __builtin_amdgcn_mfma_f32_16x16x32_bf16(a0, b, acc[0][j], 0, 0, 0);
      acc[1][j] = __builtin_amdgcn_mfma_f32_16x16x32_bf16(a1, b, acc[1][j], 0, 0, 0);
    }
  }
  #pragma unroll
  for (int ks = 0; ks < 4; ++ks){
    short8 a0 = *(const short8*)(Xb + (size_t)(m0 + lr) * 64 + q2*4 + ks*16);
    short8 a1 = *(const short8*)(Xb + (size_t)(m0 + lr + 16) * 64 + q2*4 + ks*16);
    #pragma unroll
    for (int j = 0; j < NBW; ++j){
      int nb2 = wv * NBW + j;
      short8 b = pb[((4 + ks) * NB16 + nb2) * 64];
      acc[0][j] = __builtin_amdgcn_mfma_f32_16x16x32_bf16(a0, b, acc[0][j], 0, 0, 0);
      acc[1][j] = __builtin_amdgcn_mfma_f32_16x16x32_bf16(a1, b, acc[1][j], 0, 0, 0);
    }
  }

  // ---- epilogue ----
  #pragma unroll
  for (int j = 0; j < NBW; ++j){
    int col = (wv * NBW + j) * 16 + lr;
    float S = 1.f, T;
    if constexpr (DO_BN){
      float s = bg[col] * rsqrtf(bv[col] + 1e-5f);
      S = s;
      T = (bias[col] - bm[col]) * s + bb[col];
    } else {
      T = bias[col];
    }
    #pragma unroll
    for (int r = 0; r < 4; ++r){
      int row = m0 + q2 * 4 + r;
      float y0 = acc[0][j][r] * S + T;
      float y1 = acc[1][j][r] * S + T;
      if constexpr (DO_BN){
        y0 = y0 > 0.f ? y0 : 0.f;
        y1 = y1 > 0.f ? y1 : 0.f;
        OutB[(size_t)row * DOUT + col] = f2bf(y0);
        OutB[(size_t)(row + 16) * DOUT + col] = f2bf(y1);
      } else {
        OutF[(size_t)row * DOUT + col] = y0;
        OutF[(size_t)(row + 16) * DOUT + col] = y1;
      }
    }
  }
}

extern "C" void kernel_launch(void* const* d_in, const int* in_sizes, int n_in,
                              void* d_out, int out_size, void* d_ws, size_t ws_size,
                              hipStream_t stream){
  const float* x = (const float*)d_in[0];
  const int* ei = (const int*)d_in[1];
  const float* Wl0 = (const float*)d_in[2];
  const float* Wr0 = (const float*)d_in[3];
  const float* bl0 = (const float*)d_in[4];
  const float* Wl1 = (const float*)d_in[5];
  const float* Wr1 = (const float*)d_in[6];
  const float* bl1 = (const float*)d_in[7];
  const float* Wl2 = (const float*)d_in[8];
  const float* Wr2 = (const float*)d_in[9];
  const float* bl2 = (const float*)d_in[10];
  const float* g0 = (const float*)d_in[11];
  const float* b0 = (const float*)d_in[12];
  const float* bm0 = (const float*)d_in[13];
  const float* bv0 = (const float*)d_in[14];
  const float* g1 = (const float*)d_in[15];
  const float* b1 = (const float*)d_in[16];
  const float* bm1 = (const float*)d_in[17];
  const float* bv1 = (const float*)d_in[18];

  const size_t REQUIRED = 51600000;
  if (ws_size < REQUIRED){
    k_sentinel<<<(out_size + 255) / 256, 256, 0, stream>>>((float*)d_out, out_size);
    return;
  }

  char* w = (char*)d_ws;
  size_t off = 0;
  auto alloc = [&](size_t bytes) -> char* {
    char* p = w + off; off = (off + bytes + 255) & ~(size_t)255; return p;
  };
  int* rp2 = (int*)alloc((size_t)(LEN + 1) * 4);
  unsigned* ss32 = (unsigned*)alloc((size_t)NE * 4);
  unsigned short* bp0 = (unsigned short*)alloc(8 * 8 * 64 * 8 * 2);
  unsigned short* bp1 = (unsigned short*)alloc(8 * 8 * 64 * 8 * 2);
  unsigned short* bp2 = (unsigned short*)alloc(8 * 4 * 64 * 8 * 2);
  unsigned* xb = (unsigned*)alloc((size_t)NN * 64 * 4);   // bf16x2 x; reused as h2
  unsigned short* h2 = (unsigned short*)xb;
  int* cnt2 = (int*)alloc((size_t)LEN * 4);
  int* pos2 = (int*)alloc((size_t)LEN * 4);
  int* deg  = (int*)alloc((size_t)NN * 4);
  int* bsum = (int*)alloc(NB_SCAN * 4);
  int* boff = (int*)alloc(NB_SCAN * 4);
  unsigned short* h1 = (unsigned short*)d_out;            // 25.6 MB, exactly d_out

  const int* srcI = ei;
  const int* dstI = ei + NE;

  hipMemsetAsync(cnt2, 0, (size_t)LEN * 4, stream);
  k_cvt<<<(NN * 16 + 255) / 256, 256, 0, stream>>>(x, xb);
  k_hist<<<(NE + 255) / 256, 256, 0, stream>>>(srcI, dstI, cnt2);
  k_deg<<<(NN + 255) / 256, 256, 0, stream>>>(cnt2, deg);
  k_bsum<<<NB_SCAN, 256, 0, stream>>>(cnt2, bsum, LEN);
  k_scanp<<<1, 256, 0, stream>>>(bsum, boff, NB_SCAN);
  k_scanf<<<NB_SCAN, 256, 0, stream>>>(cnt2, boff, rp2, pos2, LEN);
  k_scat<<<1024, 256, 0, stream>>>(srcI, dstI, pos2, ss32);
  k_pack<8><<<16, 256, 0, stream>>>(Wl0, Wr0, bp0);
  k_pack<8><<<16, 256, 0, stream>>>(Wl1, Wr1, bp1);
  k_pack<4><<<8, 256, 0, stream>>>(Wl2, Wr2, bp2);

  k_fused<8, true ><<<3125, 256, 0, stream>>>(xb, rp2, ss32, deg, bp0,
      bl0, g0, b0, bm0, bv0, h1, nullptr);
  k_fused<8, true ><<<3125, 256, 0, stream>>>((const unsigned*)h1, rp2, ss32, deg, bp1,
      bl1, g1, b1, bm1, bv1, h2, nullptr);
  k_fused<4, false><<<3125, 256, 0, stream>>>((const unsigned*)h2, rp2, ss32, deg, bp2,
      bl2, nullptr, nullptr, nullptr, nullptr, nullptr, (float*)d_out);
}

// Round 3
// 500.578 us; speedup vs baseline: 7.2172x; 7.2172x over previous
//
#include <hip/hip_runtime.h>

#define NN 100000
#define NE 1600000
#define DIM 128
#define NT 13            // src tiles: src>>13 -> 8192 rows = 2 MB bf16 per tile (fits 4 MB L2)
#define SH 13
#define LEN (NN * NT)    // buckets, rowgroup-major: idx = (dst>>3)*104 + tt*8 + (dst&7)
#define NB_SCAN ((LEN + 1023) / 1024)
#define FST 140          // smF row stride (dwords): 16B-aligned
#define NGRP 12500       // rowgroups (NN/8)
#define PW 8             // dst-window passes in k_scat
#define GW ((NGRP + PW - 1) / PW)

typedef __attribute__((ext_vector_type(8))) short short8;
typedef __attribute__((ext_vector_type(4))) float f4;
typedef __attribute__((ext_vector_type(2))) float f2;
typedef __attribute__((ext_vector_type(4))) unsigned u4;

__device__ __forceinline__ unsigned short f2bf(float f){
  unsigned x = __float_as_uint(f);
  x += 0x7fffu + ((x >> 16) & 1u);
  return (unsigned short)(x >> 16);
}
__device__ __forceinline__ unsigned pack2(float lo, float hi){
  return ((unsigned)f2bf(hi) << 16) | (unsigned)f2bf(lo);
}
__device__ __forceinline__ float blo(unsigned u){ return __uint_as_float(u << 16); }
__device__ __forceinline__ float bhi(unsigned u){ return __uint_as_float(u & 0xffff0000u); }
__device__ __forceinline__ short8 cvt8(f4 a, f4 b){
  short8 r;
  #pragma unroll
  for (int j = 0; j < 4; ++j){ r[j] = (short)f2bf(a[j]); r[j+4] = (short)f2bf(b[j]); }
  return r;
}

// ---------------- fallback sentinel ----------------
__global__ void k_sentinel(float* __restrict__ out, int n){
  int i = blockIdx.x * blockDim.x + threadIdx.x;
  if (i < n) out[i] = 12345.0f;
}

// ---------------- x fp32 -> bf16x2 ----------------
__global__ void k_cvt(const float* __restrict__ x, unsigned* __restrict__ xb){
  int i = blockIdx.x * blockDim.x + threadIdx.x;   // i < NN*16
  if (i >= NN * 16) return;
  f4 a = ((const f4*)x)[2 * i];
  f4 b = ((const f4*)x)[2 * i + 1];
  u4 o;
  o[0] = pack2(a[0], a[1]); o[1] = pack2(a[2], a[3]);
  o[2] = pack2(b[0], b[1]); o[3] = pack2(b[2], b[3]);
  ((u4*)xb)[i] = o;
}

// ---------------- histogram (rowgroup-major buckets) ----------------
__global__ void k_hist(const int* __restrict__ src, const int* __restrict__ dst,
                       int* __restrict__ cnt){
  int i = blockIdx.x * blockDim.x + threadIdx.x;
  if (i < NE){
    int s = src[i], d = dst[i];
    atomicAdd(&cnt[(d >> 3) * 104 + (s >> SH) * 8 + (d & 7)], 1);
  }
}

__global__ void k_deg(const int* __restrict__ cnt, int* __restrict__ deg){
  int i = blockIdx.x * blockDim.x + threadIdx.x;
  if (i < NN){
    int g = i >> 3, r = i & 7;
    int s = 0;
    #pragma unroll
    for (int tt = 0; tt < NT; ++tt) s += cnt[g * 104 + tt * 8 + r];
    deg[i] = s;
  }
}

__global__ void k_bsum(const int* __restrict__ cnt, int* __restrict__ bsum, int len){
  __shared__ int sh[256];
  int t = threadIdx.x, b = blockIdx.x;
  int base = b * 1024 + t * 4;
  int s = 0;
  #pragma unroll
  for (int j = 0; j < 4; ++j){ int i = base + j; if (i < len) s += cnt[i]; }
  sh[t] = s; __syncthreads();
  for (int off = 128; off > 0; off >>= 1){
    if (t < off) sh[t] += sh[t + off];
    __syncthreads();
  }
  if (t == 0) bsum[b] = sh[0];
}

__global__ void k_scanp(const int* __restrict__ bsum, int* __restrict__ boff, int nb){
  __shared__ int sh[256];
  int t = threadIdx.x;
  int chunk = (nb + 255) / 256;
  int s = 0;
  for (int j = 0; j < chunk; ++j){ int i = t * chunk + j; if (i < nb) s += bsum[i]; }
  sh[t] = s; __syncthreads();
  int tin = s;
  for (int off = 1; off < 256; off <<= 1){
    int u = (t >= off) ? sh[t - off] : 0;
    __syncthreads();
    sh[t] += u;
    __syncthreads();
  }
  int run = sh[t] - tin;
  for (int j = 0; j < chunk; ++j){
    int i = t * chunk + j;
    if (i < nb){ boff[i] = run; run += bsum[i]; }
  }
}

__global__ void k_scanf(const int* __restrict__ cnt, const int* __restrict__ boff,
                        int* __restrict__ rp, int* __restrict__ pos, int len){
  __shared__ int sh[256];
  int t = threadIdx.x, b = blockIdx.x;
  int base = b * 1024 + t * 4;
  int c[4]; int s = 0;
  #pragma unroll
  for (int j = 0; j < 4; ++j){ int i = base + j; c[j] = (i < len) ? cnt[i] : 0; s += c[j]; }
  sh[t] = s; __syncthreads();
  int tin = s;
  for (int off = 1; off < 256; off <<= 1){
    int u = (t >= off) ? sh[t - off] : 0;
    __syncthreads();
    sh[t] += u;
    __syncthreads();
  }
  int run = boff[b] + sh[t] - tin;
  #pragma unroll
  for (int j = 0; j < 4; ++j){
    int i = base + j;
    if (i < len){
      rp[i] = run; pos[i] = run; run += c[j];
      if (i == len - 1) rp[len] = run;
    }
  }
}

// ---------------- direct dst-windowed scatter to ss32 -------------------------
// PW sequential passes; pass p writes only rowgroups [p*GW,(p+1)*GW) ->
// contiguous window stays L2-resident. Records are fully resolved:
// rec = (src<<8) | (dst&7)  -- src*256 is the Xb byte offset, low 3 bits the
// LDS accumulator row. k_fused needs NO tile bookkeeping at consume time.
__global__ __launch_bounds__(256)
void k_scat(const int* __restrict__ src, const int* __restrict__ dst,
            int* __restrict__ pos, unsigned* __restrict__ ss32){
  int tid = blockIdx.x * 256 + threadIdx.x;
  int stride = gridDim.x * 256;
  for (int p = 0; p < PW; ++p){
    int glo = p * GW, ghi = glo + GW;
    for (int i = tid; i < NE; i += stride){
      int d = dst[i];
      int g = d >> 3;
      if (g >= glo && g < ghi){
        int s = src[i];
        int b = g * 104 + ((s >> SH) << 3) + (d & 7);
        int q = atomicAdd(&pos[b], 1);
        ss32[q] = ((unsigned)s << 8) | (unsigned)(d & 7);
      }
    }
  }
}

// ---------------- W packing ----------------
template<int NB16>
__global__ void k_pack(const float* __restrict__ Wl,
                       const float* __restrict__ Wr,
                       unsigned short* __restrict__ Bp){
  constexpr int DOUT = NB16 * 16;
  int idx = blockIdx.x * blockDim.x + threadIdx.x;
  if (idx >= 8 * NB16 * 64) return;
  int lane = idx & 63;
  int nb = (idx >> 6) % NB16;
  int ks = idx / (64 * NB16);
  int n = nb * 16 + (lane & 15);
  int k0 = ks * 32 + (lane >> 4) * 8;
  short8 v;
  #pragma unroll
  for (int j = 0; j < 8; ++j){
    int k = k0 + j;
    float w = (k < 128) ? Wl[k * DOUT + n] : Wr[(k - 128) * DOUT + n];
    v[j] = (short)f2bf(w);
  }
  ((short8*)Bp)[idx] = v;
}

// ---------------- fused tiled mean-aggregate + dual-GEMM (+BN+ReLU) ----------
// Per edge (wave-cooperative): 1 coalesced 256B bf16 row load + plain LDS
// read-modify-write (ds_read_b64 + 2 v_add + ds_write_b64). NO atomics needed:
// each wave owns rows [wv*8, wv*8+8) exclusively and each lane owns dword
// columns 2*lane..2*lane+1 exclusively, so the RMW is race-free and is
// guaranteed to lower to DS ops (R2's atomicAdd on a generic pointer lowered
// to flat atomics -> 14x regression). ~6 VALU + 2 DS ops per edge vs R1's
// ~20 VALU + shfl-based tile walk + flush branch.
template<int NB16, bool DO_BN>
__global__ __launch_bounds__(256, 8)
void k_fused(const unsigned* __restrict__ Xb,
             const int* __restrict__ rp2, const unsigned* __restrict__ ss32,
             const int* __restrict__ deg,
             const unsigned short* __restrict__ Bp,
             const float* __restrict__ bias,
             const float* __restrict__ bg, const float* __restrict__ bb,
             const float* __restrict__ bm, const float* __restrict__ bv,
             unsigned short* __restrict__ OutB, float* __restrict__ OutF){
  constexpr int DOUT = NB16 * 16;
  constexpr int NBW = NB16 / 4;
  __shared__ float smF[32][FST];
  const int t = threadIdx.x;
  const int lane = t & 63;
  const int wv = t >> 6;
  const int m0 = blockIdx.x * 32;
  const int g = blockIdx.x * 4 + wv;      // rowgroup owned by this wave

  for (int i = t; i < 32 * FST; i += 256) (&smF[0][0])[i] = 0.f;
  __syncthreads();

  float* const base = &smF[wv * 8][0];
  const char* const Xc = (const char*)Xb;
  const unsigned lane4 = (unsigned)lane * 4u;

  int e   = rp2[g * 104];
  int end = rp2[g * 104 + 104];

  #define EDGE(rec) { \
    unsigned _u = *(const unsigned*)(Xc + ((rec) & 0xFFFFFF00u) + lane4); \
    float* _p = base + ((rec) & 7u) * FST + 2 * lane; \
    f2 _v = *(const f2*)_p; \
    _v[0] += blo(_u); _v[1] += bhi(_u); \
    *(f2*)_p = _v; }

  // head peel to 16B record alignment
  while (e < end && (e & 3)){
    unsigned rec = (unsigned)__builtin_amdgcn_readfirstlane((int)ss32[e]);
    EDGE(rec);
    ++e;
  }
  // body: 8 records per iteration (two aligned 16B record loads);
  // gathers issued as a batch, then 8 race-free LDS RMWs
  while (e + 8 <= end){
    u4 qa = *(const u4*)(ss32 + e);
    u4 qb = *(const u4*)(ss32 + e + 4);
    unsigned r[8];
    r[0] = (unsigned)__builtin_amdgcn_readfirstlane((int)qa[0]);
    r[1] = (unsigned)__builtin_amdgcn_readfirstlane((int)qa[1]);
    r[2] = (unsigned)__builtin_amdgcn_readfirstlane((int)qa[2]);
    r[3] = (unsigned)__builtin_amdgcn_readfirstlane((int)qa[3]);
    r[4] = (unsigned)__builtin_amdgcn_readfirstlane((int)qb[0]);
    r[5] = (unsigned)__builtin_amdgcn_readfirstlane((int)qb[1]);
    r[6] = (unsigned)__builtin_amdgcn_readfirstlane((int)qb[2]);
    r[7] = (unsigned)__builtin_amdgcn_readfirstlane((int)qb[3]);
    unsigned u[8];
    #pragma unroll
    for (int i = 0; i < 8; ++i)
      u[i] = *(const unsigned*)(Xc + (r[i] & 0xFFFFFF00u) + lane4);
    #pragma unroll
    for (int i = 0; i < 8; ++i){
      float* p = base + (r[i] & 7u) * FST + 2 * lane;
      f2 v = *(const f2*)p;
      v[0] += blo(u[i]);
      v[1] += bhi(u[i]);
      *(f2*)p = v;
    }
    e += 8;
  }
  // tail
  while (e < end){
    unsigned rec = (unsigned)__builtin_amdgcn_readfirstlane((int)ss32[e]);
    EDGE(rec);
    ++e;
  }
  #undef EDGE
  __syncthreads();

  // normalize
  {
    int row = t >> 3;
    int d = deg[m0 + row];
    float inv = (d > 0) ? 1.f / (float)d : 0.f;
    float* pr = &smF[row][(t & 7) * 16];
    #pragma unroll
    for (int i = 0; i < 16; ++i) pr[i] *= inv;
  }
  __syncthreads();

  // ---- phase 2: dual GEMM ----
  const int q2 = lane >> 4, lr = lane & 15;
  const short8* pb = (const short8*)Bp + lane;
  f4 acc[2][NBW];
  #pragma unroll
  for (int gg = 0; gg < 2; ++gg)
    #pragma unroll
    for (int j = 0; j < NBW; ++j)
      acc[gg][j] = (f4){0.f, 0.f, 0.f, 0.f};

  #pragma unroll
  for (int ks = 0; ks < 4; ++ks){
    const float* r0 = &smF[lr][ks * 32 + q2 * 8];
    const float* r1 = &smF[lr + 16][ks * 32 + q2 * 8];
    short8 a0 = cvt8(*(const f4*)r0, *(const f4*)(r0 + 4));
    short8 a1 = cvt8(*(const f4*)r1, *(const f4*)(r1 + 4));
    #pragma unroll
    for (int j = 0; j < NBW; ++j){
      int nb2 = wv * NBW + j;
      short8 b = pb[(ks * NB16 + nb2) * 64];
      acc[0][j] = __builtin_amdgcn_mfma_f32_16x16x32_bf16(a0, b, acc[0][j], 0, 0, 0);
      acc[1][j] = __builtin_amdgcn_mfma_f32_16x16x32_bf16(a1, b, acc[1][j], 0, 0, 0);
    }
  }
  #pragma unroll
  for (int ks = 0; ks < 4; ++ks){
    short8 a0 = *(const short8*)(Xb + (size_t)(m0 + lr) * 64 + q2*4 + ks*16);
    short8 a1 = *(const short8*)(Xb + (size_t)(m0 + lr + 16) * 64 + q2*4 + ks*16);
    #pragma unroll
    for (int j = 0; j < NBW; ++j){
      int nb2 = wv * NBW + j;
      short8 b = pb[((4 + ks) * NB16 + nb2) * 64];
      acc[0][j] = __builtin_amdgcn_mfma_f32_16x16x32_bf16(a0, b, acc[0][j], 0, 0, 0);
      acc[1][j] = __builtin_amdgcn_mfma_f32_16x16x32_bf16(a1, b, acc[1][j], 0, 0, 0);
    }
  }

  // ---- epilogue ----
  #pragma unroll
  for (int j = 0; j < NBW; ++j){
    int col = (wv * NBW + j) * 16 + lr;
    float S = 1.f, T;
    if constexpr (DO_BN){
      float s = bg[col] * rsqrtf(bv[col] + 1e-5f);
      S = s;
      T = (bias[col] - bm[col]) * s + bb[col];
    } else {
      T = bias[col];
    }
    #pragma unroll
    for (int r = 0; r < 4; ++r){
      int row = m0 + q2 * 4 + r;
      float y0 = acc[0][j][r] * S + T;
      float y1 = acc[1][j][r] * S + T;
      if constexpr (DO_BN){
        y0 = y0 > 0.f ? y0 : 0.f;
        y1 = y1 > 0.f ? y1 : 0.f;
        OutB[(size_t)row * DOUT + col] = f2bf(y0);
        OutB[(size_t)(row + 16) * DOUT + col] = f2bf(y1);
      } else {
        OutF[(size_t)row * DOUT + col] = y0;
        OutF[(size_t)(row + 16) * DOUT + col] = y1;
      }
    }
  }
}

extern "C" void kernel_launch(void* const* d_in, const int* in_sizes, int n_in,
                              void* d_out, int out_size, void* d_ws, size_t ws_size,
                              hipStream_t stream){
  const float* x = (const float*)d_in[0];
  const int* ei = (const int*)d_in[1];
  const float* Wl0 = (const float*)d_in[2];
  const float* Wr0 = (const float*)d_in[3];
  const float* bl0 = (const float*)d_in[4];
  const float* Wl1 = (const float*)d_in[5];
  const float* Wr1 = (const float*)d_in[6];
  const float* bl1 = (const float*)d_in[7];
  const float* Wl2 = (const float*)d_in[8];
  const float* Wr2 = (const float*)d_in[9];
  const float* bl2 = (const float*)d_in[10];
  const float* g0 = (const float*)d_in[11];
  const float* b0 = (const float*)d_in[12];
  const float* bm0 = (const float*)d_in[13];
  const float* bv0 = (const float*)d_in[14];
  const float* g1 = (const float*)d_in[15];
  const float* b1 = (const float*)d_in[16];
  const float* bm1 = (const float*)d_in[17];
  const float* bv1 = (const float*)d_in[18];

  const size_t REQUIRED = 51600000;
  if (ws_size < REQUIRED){
    k_sentinel<<<(out_size + 255) / 256, 256, 0, stream>>>((float*)d_out, out_size);
    return;
  }

  char* w = (char*)d_ws;
  size_t off = 0;
  auto alloc = [&](size_t bytes) -> char* {
    char* p = w + off; off = (off + bytes + 255) & ~(size_t)255; return p;
  };
  int* rp2 = (int*)alloc((size_t)(LEN + 1) * 4);
  unsigned* ss32 = (unsigned*)alloc((size_t)NE * 4);
  unsigned short* bp0 = (unsigned short*)alloc(8 * 8 * 64 * 8 * 2);
  unsigned short* bp1 = (unsigned short*)alloc(8 * 8 * 64 * 8 * 2);
  unsigned short* bp2 = (unsigned short*)alloc(8 * 4 * 64 * 8 * 2);
  unsigned* xb = (unsigned*)alloc((size_t)NN * 64 * 4);   // bf16x2 x; reused as h2
  unsigned short* h2 = (unsigned short*)xb;
  int* cnt2 = (int*)alloc((size_t)LEN * 4);
  int* pos2 = (int*)alloc((size_t)LEN * 4);
  int* deg  = (int*)alloc((size_t)NN * 4);
  int* bsum = (int*)alloc(NB_SCAN * 4);
  int* boff = (int*)alloc(NB_SCAN * 4);
  unsigned short* h1 = (unsigned short*)d_out;            // 25.6 MB, exactly d_out

  const int* srcI = ei;
  const int* dstI = ei + NE;

  hipMemsetAsync(cnt2, 0, (size_t)LEN * 4, stream);
  k_cvt<<<(NN * 16 + 255) / 256, 256, 0, stream>>>(x, xb);
  k_hist<<<(NE + 255) / 256, 256, 0, stream>>>(srcI, dstI, cnt2);
  k_deg<<<(NN + 255) / 256, 256, 0, stream>>>(cnt2, deg);
  k_bsum<<<NB_SCAN, 256, 0, stream>>>(cnt2, bsum, LEN);
  k_scanp<<<1, 256, 0, stream>>>(bsum, boff, NB_SCAN);
  k_scanf<<<NB_SCAN, 256, 0, stream>>>(cnt2, boff, rp2, pos2, LEN);
  k_scat<<<1024, 256, 0, stream>>>(srcI, dstI, pos2, ss32);
  k_pack<8><<<16, 256, 0, stream>>>(Wl0, Wr0, bp0);
  k_pack<8><<<16, 256, 0, stream>>>(Wl1, Wr1, bp1);
  k_pack<4><<<8, 256, 0, stream>>>(Wl2, Wr2, bp2);

  k_fused<8, true ><<<3125, 256, 0, stream>>>(xb, rp2, ss32, deg, bp0,
      bl0, g0, b0, bm0, bv0, h1, nullptr);
  k_fused<8, true ><<<3125, 256, 0, stream>>>((const unsigned*)h1, rp2, ss32, deg, bp1,
      bl1, g1, b1, bm1, bv1, h2, nullptr);
  k_fused<4, false><<<3125, 256, 0, stream>>>((const unsigned*)h2, rp2, ss32, deg, bp2,
      bl2, nullptr, nullptr, nullptr, nullptr, nullptr, (float*)d_out);
}